// Round 6
// baseline (351.533 us; speedup 1.0000x reference)
//
#include <hip/hip_runtime.h>
#include <hip/hip_fp16.h>
#include <cstddef>
#include <cstdint>

// Problem constants (fixed by reference setup_inputs)
#define DMODEL 256
#define NHEAD  8
#define NLVL   4
#define NPT    4
#define DHEAD  32
#define DFFN   1024
#define SLEN   5440
#define BATCH  4
#define NTOK   (BATCH * SLEN)   // 21760 = 340*64
#define NT256  ((size_t)NTOK * 256)
#define LN_EPS 1e-5f

typedef __attribute__((ext_vector_type(4))) float f32x4;
typedef __attribute__((ext_vector_type(8))) short s16x8;

__device__ __forceinline__ unsigned short f2bf(float f) {
    union { float f; unsigned u; } v; v.f = f;
    unsigned u = v.u;
    u += 0x7FFFu + ((u >> 16) & 1u);   // round-to-nearest-even
    return (unsigned short)(u >> 16);
}
__device__ __forceinline__ float bf2f(unsigned short h) {
    union { unsigned u; float f; } v; v.u = ((unsigned)h) << 16;
    return v.f;
}

// ---------------------------------------------------------------------------
// prep: srcB = bf16(src); qB = bf16(src + pos)
// ---------------------------------------------------------------------------
__global__ __launch_bounds__(256) void prep_kernel(
    const float* __restrict__ src, const float* __restrict__ pos,
    unsigned short* __restrict__ srcB, unsigned short* __restrict__ qB)
{
    const size_t i = ((size_t)blockIdx.x * 256 + threadIdx.x) * 4;
    const float4 s = *(const float4*)(src + i);
    const float4 p = *(const float4*)(pos + i);
    ushort4 sb, qb;
    sb.x = f2bf(s.x); sb.y = f2bf(s.y); sb.z = f2bf(s.z); sb.w = f2bf(s.w);
    qb.x = f2bf(s.x + p.x); qb.y = f2bf(s.y + p.y);
    qb.z = f2bf(s.z + p.z); qb.w = f2bf(s.w + p.w);
    *(ushort4*)(srcB + i) = sb;
    *(ushort4*)(qB + i) = qb;
}

// ---------------------------------------------------------------------------
// All weight transposes in ONE launch. W [K][N] fp32 -> Wt [N][K] bf16.
// Woff and Wa go into ONE concatenated WcatT [384][256] (rows 256.. = Wa).
// ---------------------------------------------------------------------------
__global__ __launch_bounds__(256) void transpose_all_kernel(
    const float* __restrict__ Wv, const float* __restrict__ Woff,
    const float* __restrict__ Wa, const float* __restrict__ Wo,
    const float* __restrict__ W1, const float* __restrict__ W2,
    unsigned short* __restrict__ WvT, unsigned short* __restrict__ WcatT,
    unsigned short* __restrict__ WoT,
    unsigned short* __restrict__ W1T, unsigned short* __restrict__ W2T)
{
    const int bid = blockIdx.x;
    const float* W; unsigned short* Wt; int K, N, t;
    if (bid < 16)       { W = Wv;   Wt = WvT;              K = 256;  N = 256;  t = bid; }
    else if (bid < 32)  { W = Woff; Wt = WcatT;            K = 256;  N = 256;  t = bid - 16; }
    else if (bid < 40)  { W = Wa;   Wt = WcatT + 256*256;  K = 256;  N = 128;  t = bid - 32; }
    else if (bid < 56)  { W = Wo;   Wt = WoT;              K = 256;  N = 256;  t = bid - 40; }
    else if (bid < 120) { W = W1;   Wt = W1T;              K = 256;  N = 1024; t = bid - 56; }
    else                { W = W2;   Wt = W2T;              K = 1024; N = 256;  t = bid - 120; }
    const int ntx = N >> 6;
    const int k0 = (t / ntx) * 64, n0 = (t % ntx) * 64;

    __shared__ float T[64][65];
    const int r  = threadIdx.x >> 4;
    const int c4 = (threadIdx.x & 15) * 4;
    #pragma unroll
    for (int rep = 0; rep < 4; rep++) {
        const int k = rep * 16 + r;
        const float4 v = *(const float4*)(W + (size_t)(k0 + k) * N + n0 + c4);
        T[c4 + 0][k] = v.x; T[c4 + 1][k] = v.y;
        T[c4 + 2][k] = v.z; T[c4 + 3][k] = v.w;
    }
    __syncthreads();
    #pragma unroll
    for (int rep = 0; rep < 4; rep++) {
        const int n = rep * 16 + r;
        ushort4 o;
        o.x = f2bf(T[n][c4 + 0]); o.y = f2bf(T[n][c4 + 1]);
        o.z = f2bf(T[n][c4 + 2]); o.w = f2bf(T[n][c4 + 3]);
        *(ushort4*)(Wt + (size_t)(n0 + n) * K + k0 + c4) = o;
    }
}

// ---------------------------------------------------------------------------
// High-MLP bf16 MFMA GEMM. C[m,n] = act(A.Bt + bias)
// A [M][K] bf16 (HBM): staged per 64-row x 256-k chunk into padded LDS
//   (8 independent 16B loads/thread -> deep vmcnt queue).
// Bt [N][K] bf16 (weights, L2-resident): loaded DIRECT from global in the
//   K-loop with pure immediate offsets (zero VALU, ~200cy L2 latency hidden
//   by 16 waves/CU).
// Block 256 thr = 4 waves, each 32 rows x 64 cols (2x4 MFMA frags).
// Grid (N/128, M/64). 33KB LDS + launch_bounds(256,4) -> 4 blocks/CU.
// OM: 0=f32, 1=bf16, 2=f16. Bias split at bsplit (col>=bsplit -> bias2).
// ---------------------------------------------------------------------------
#define LDA 264   // 256 + 8 halves pad: row stride 132 dw = 4 mod 32 banks

template <bool RELU, int OM>
__global__ __launch_bounds__(256, 4) void gemm_as_kernel(
    const unsigned short* __restrict__ A,
    const unsigned short* __restrict__ Bt,
    const float* __restrict__ bias, const float* __restrict__ bias2,
    int bsplit,
    void* __restrict__ Cout, int M, int N, int K)
{
    __shared__ __align__(16) unsigned short sA[64 * LDA];  // 33 KB

    const int tid  = threadIdx.x;
    const int w    = tid >> 6;
    const int lane = tid & 63;
    const int wm   = (w >> 1) * 32;
    const int wn   = (w & 1) * 64;
    const int row0 = blockIdx.y * 64;
    const int col0 = blockIdx.x * 128;
    const int m16  = lane & 15;
    const int q    = lane >> 4;

    // staging map: iter c covers rows c*8 + (tid>>5), k = (tid&31)*8
    const int sr = tid >> 5;
    const int sk = (tid & 31) * 8;
    const unsigned short* ag = A + (size_t)(row0 + sr) * K + sk;
    unsigned short* swp = &sA[sr * LDA + sk];

    // B fragment base pointers (per col-frag); K-loop uses imm offsets only
    const unsigned short* bg[4];
    #pragma unroll
    for (int j = 0; j < 4; j++)
        bg[j] = Bt + (size_t)(col0 + wn + j * 16 + m16) * K + q * 8;

    f32x4 acc[2][4];
    #pragma unroll
    for (int i = 0; i < 2; i++)
        #pragma unroll
        for (int j = 0; j < 4; j++)
            acc[i][j] = (f32x4){0.f, 0.f, 0.f, 0.f};

    for (int ks = 0; ks < K; ks += 256) {
        __syncthreads();   // previous chunk's readers done (no-op first pass)
        int4 stg[8];
        #pragma unroll
        for (int c = 0; c < 8; c++)
            stg[c] = *(const int4*)(ag + (size_t)c * 8 * K);
        #pragma unroll
        for (int c = 0; c < 8; c++)
            *(int4*)(swp + c * 8 * LDA) = stg[c];
        ag += 256;
        __syncthreads();

        #pragma unroll
        for (int kk = 0; kk < 8; kk++) {
            s16x8 af[2], bf[4];
            #pragma unroll
            for (int i = 0; i < 2; i++)
                af[i] = *(const s16x8*)&sA[(wm + i * 16 + m16) * LDA + kk * 32 + q * 8];
            #pragma unroll
            for (int j = 0; j < 4; j++)
                bf[j] = *(const s16x8*)(bg[j] + kk * 32);
            #pragma unroll
            for (int i = 0; i < 2; i++)
                #pragma unroll
                for (int j = 0; j < 4; j++)
                    acc[i][j] = __builtin_amdgcn_mfma_f32_16x16x32_bf16(
                        af[i], bf[j], acc[i][j], 0, 0, 0);
        }
        #pragma unroll
        for (int j = 0; j < 4; j++) bg[j] += 256;
    }

    // epilogue: D layout col=lane&15, row=(lane>>4)*4+reg (m89/m91-verified)
    #pragma unroll
    for (int i = 0; i < 2; i++) {
        #pragma unroll
        for (int j = 0; j < 4; j++) {
            const int col = col0 + wn + j * 16 + m16;
            const float bcol = (col < bsplit) ? bias[col] : bias2[col - bsplit];
            #pragma unroll
            for (int r = 0; r < 4; r++) {
                const int row = row0 + wm + i * 16 + q * 4 + r;
                float v = acc[i][j][r] + bcol;
                if (RELU) v = fmaxf(v, 0.f);
                if (OM == 1)
                    ((unsigned short*)Cout)[(size_t)row * N + col] = f2bf(v);
                else if (OM == 2)
                    ((__half*)Cout)[(size_t)row * N + col] = __float2half(v);
                else
                    ((float*)Cout)[(size_t)row * N + col] = v;
            }
        }
    }
}

// ---------------------------------------------------------------------------
// MSDA meta kernel: one thread per (bq, h, p). Softmax via 16-lane shfl.
// Reads fused olg [NTOK][384] (cols 0..255 = offsets, 256..383 = logits).
// meta[bq][p][h] = uint4 { idx0|idx1<<16, idx2|idx3<<16, half2(w0,w1), half2(w2,w3) }
// ---------------------------------------------------------------------------
__global__ __launch_bounds__(256) void msda_meta_kernel(
    const float* __restrict__ olg, uint4* __restrict__ meta)
{
    const int t  = blockIdx.x * 256 + threadIdx.x;   // [0, NTOK*128)
    const int p  = t & 15;
    const int h  = (t >> 4) & 7;
    const int bq = t >> 7;
    const int b  = bq / SLEN;
    const int q  = bq - b * SLEN;

    int rem, Wq;
    if (q < 4096)      { rem = q;        Wq = 64; }
    else if (q < 5120) { rem = q - 4096; Wq = 32; }
    else if (q < 5376) { rem = q - 5120; Wq = 16; }
    else               { rem = q - 5376; Wq = 8;  }
    const int gy = rem / Wq;
    const int gx = rem - gy * Wq;
    const float ref_x = (gx + 0.5f) / (float)Wq;
    const float ref_y = (gy + 0.5f) / (float)Wq;

    const float lg = olg[(size_t)bq * 384 + 256 + h * 16 + p];
    float mx = lg;
    #pragma unroll
    for (int m = 1; m < 16; m <<= 1) mx = fmaxf(mx, __shfl_xor(mx, m));
    const float e = expf(lg - mx);
    float s = e;
    #pragma unroll
    for (int m = 1; m < 16; m <<= 1) s += __shfl_xor(s, m);
    const float aw = e / s;

    const float2 o2 = *(const float2*)(olg + (size_t)bq * 384 + h * 32 + 2 * p);

    const int l = p >> 2;
    constexpr int LW[4] = {64, 32, 16, 8};
    constexpr int LS[4] = {0, 4096, 5120, 5376};
    const int Wl = LW[l];
    const float fW = (float)Wl;

    // mirror reference arithmetic exactly: (ref + off/W)*W - 0.5
    const float X = (ref_x + o2.x / fW) * fW - 0.5f;
    const float Y = (ref_y + o2.y / fW) * fW - 0.5f;
    const float x0f = floorf(X), y0f = floorf(Y);
    const float fx = X - x0f, fy = Y - y0f;
    const int x0 = (int)x0f, y0 = (int)y0f;

    unsigned idx[4]; __half hw[4];
    #pragma unroll
    for (int dy = 0; dy < 2; dy++) {
        const int yi = y0 + dy;
        const float wy = dy ? fy : (1.f - fy);
        const bool vy = (yi >= 0) && (yi < Wl);
        const int yc = min(max(yi, 0), Wl - 1);
        #pragma unroll
        for (int dx = 0; dx < 2; dx++) {
            const int xi = x0 + dx;
            const float wx = dx ? fx : (1.f - fx);
            const bool vx = (xi >= 0) && (xi < Wl);
            const int xc = min(max(xi, 0), Wl - 1);
            const int c = dy * 2 + dx;
            idx[c] = (unsigned)(LS[l] + yc * Wl + xc);   // < 5440, fits u16
            hw[c] = __float2half((vx && vy) ? (aw * wx * wy) : 0.f);
        }
    }
    union { __half2 h2; unsigned u; } pk0, pk1;
    pk0.h2 = __halves2half2(hw[0], hw[1]);
    pk1.h2 = __halves2half2(hw[2], hw[3]);
    uint4 m;
    m.x = idx[0] | (idx[1] << 16);
    m.y = idx[2] | (idx[3] << 16);
    m.z = pk0.u;
    m.w = pk1.u;
    meta[((size_t)bq * 16 + p) * 8 + h] = m;
}

// ---------------------------------------------------------------------------
// MSDA gather: block = 8 tokens; lane = 8 channels (16B) of one head.
// ---------------------------------------------------------------------------
__global__ __launch_bounds__(256) void msda_sample_kernel(
    const __half* __restrict__ value, const uint4* __restrict__ meta,
    unsigned short* __restrict__ out)
{
    const int tid = threadIdx.x;
    const int sub = tid & 3;
    const int h   = (tid >> 2) & 7;
    const int t8  = tid >> 5;
    const int bq  = blockIdx.x * 8 + t8;
    const int b   = (blockIdx.x * 8) / SLEN;     // uniform per block (5440%8==0)

    const char* vb = (const char*)value + (size_t)b * SLEN * 512;
    const unsigned laneoff = (unsigned)(h * 64 + sub * 16);
    const uint4* metap = meta + (size_t)bq * 128 + h;   // index with p*8

    __half2 acc[4][4];
    #pragma unroll
    for (int i = 0; i < 4; i++)
        #pragma unroll
        for (int k = 0; k < 4; k++)
            acc[i][k] = __float2half2_rn(0.f);

    for (int g = 0; g < 4; g++) {
        #pragma unroll
        for (int pp = 0; pp < 4; pp++) {
            const int p = g * 4 + pp;
            const uint4 m = metap[p * 8];
            const unsigned a0 = ((m.x & 0xFFFFu) << 9) + laneoff;
            const unsigned a1 = ((m.x >> 16) << 9) + laneoff;
            const unsigned a2 = ((m.y & 0xFFFFu) << 9) + laneoff;
            const unsigned a3 = ((m.y >> 16) << 9) + laneoff;
            const int4 v0 = *(const int4*)(vb + a0);
            const int4 v1 = *(const int4*)(vb + a1);
            const int4 v2 = *(const int4*)(vb + a2);
            const int4 v3 = *(const int4*)(vb + a3);
            union { unsigned u; __half2 h2; } wz, ww;
            wz.u = m.z; ww.u = m.w;
            const __half2 ws0 = __half2half2(__low2half(wz.h2));
            const __half2 ws1 = __half2half2(__high2half(wz.h2));
            const __half2 ws2 = __half2half2(__low2half(ww.h2));
            const __half2 ws3 = __half2half2(__high2half(ww.h2));
            const __half2* p0 = (const __half2*)&v0;
            const __half2* p1 = (const __half2*)&v1;
            const __half2* p2 = (const __half2*)&v2;
            const __half2* p3 = (const __half2*)&v3;
            #pragma unroll
            for (int k = 0; k < 4; k++) {
                acc[pp][k] = __hfma2(ws0, p0[k], acc[pp][k]);
                acc[pp][k] = __hfma2(ws1, p1[k], acc[pp][k]);
                acc[pp][k] = __hfma2(ws2, p2[k], acc[pp][k]);
                acc[pp][k] = __hfma2(ws3, p3[k], acc[pp][k]);
            }
        }
    }

    uint4 o;
    unsigned* ou = &o.x;
    #pragma unroll
    for (int k = 0; k < 4; k++) {
        float2 s = {0.f, 0.f};
        #pragma unroll
        for (int i = 0; i < 4; i++) {
            const float2 f = __half22float2(acc[i][k]);
            s.x += f.x; s.y += f.y;
        }
        ou[k] = (unsigned)f2bf(s.x) | ((unsigned)f2bf(s.y) << 16);
    }
    *(uint4*)(out + (size_t)bq * 256 + h * 32 + sub * 8) = o;
}

// ---------------------------------------------------------------------------
// Fused residual-add + LayerNorm. One wave per row, 4 rows/block.
// X1B: x1 is bf16 (else fp32). WF: write fp32 out. WB: write bf16 out.
// ---------------------------------------------------------------------------
template <bool X1B, bool WF, bool WB>
__global__ __launch_bounds__(256) void ln_kernel(
    const void* __restrict__ x1, const float* __restrict__ x2,
    const float* __restrict__ g, const float* __restrict__ be,
    float* __restrict__ outf, unsigned short* __restrict__ outb)
{
    const int lane = threadIdx.x & 63;
    const int wid  = threadIdx.x >> 6;
    const size_t row  = (size_t)blockIdx.x * 4 + wid;
    const size_t base = row * 256 + lane * 4;

    float a0, a1, a2, a3;
    if (X1B) {
        const ushort4 a = *(const ushort4*)((const unsigned short*)x1 + base);
        a0 = bf2f(a.x); a1 = bf2f(a.y); a2 = bf2f(a.z); a3 = bf2f(a.w);
    } else {
        const float4 a = *(const float4*)((const float*)x1 + base);
        a0 = a.x; a1 = a.y; a2 = a.z; a3 = a.w;
    }
    const float4 b = *(const float4*)(x2 + base);
    const float v0 = a0 + b.x, v1 = a1 + b.y, v2 = a2 + b.z, v3 = a3 + b.w;

    float s  = v0 + v1 + v2 + v3;
    float s2 = v0 * v0 + v1 * v1 + v2 * v2 + v3 * v3;
    #pragma unroll
    for (int o = 32; o > 0; o >>= 1) {
        s  += __shfl_xor(s, o);
        s2 += __shfl_xor(s2, o);
    }
    const float mu  = s * (1.f / 256.f);
    const float var = s2 * (1.f / 256.f) - mu * mu;
    const float r   = rsqrtf(var + LN_EPS);

    const float4 gv = *(const float4*)(g  + lane * 4);
    const float4 bv = *(const float4*)(be + lane * 4);
    float4 o4;
    o4.x = (v0 - mu) * r * gv.x + bv.x;
    o4.y = (v1 - mu) * r * gv.y + bv.y;
    o4.z = (v2 - mu) * r * gv.z + bv.z;
    o4.w = (v3 - mu) * r * gv.w + bv.w;
    if (WF) *(float4*)(outf + base) = o4;
    if (WB) {
        ushort4 ob;
        ob.x = f2bf(o4.x); ob.y = f2bf(o4.y); ob.z = f2bf(o4.z); ob.w = f2bf(o4.w);
        *(ushort4*)(outb + base) = ob;
    }
}

// ---------------------------------------------------------------------------
extern "C" void kernel_launch(void* const* d_in, const int* in_sizes, int n_in,
                              void* d_out, int out_size, void* d_ws, size_t ws_size,
                              hipStream_t stream)
{
    const float* src  = (const float*)d_in[0];
    const float* pos  = (const float*)d_in[1];
    const float* Wv   = (const float*)d_in[4];
    const float* bv   = (const float*)d_in[5];
    const float* Woff = (const float*)d_in[6];
    const float* boff = (const float*)d_in[7];
    const float* Wa   = (const float*)d_in[8];
    const float* ba   = (const float*)d_in[9];
    const float* Wo   = (const float*)d_in[10];
    const float* bo   = (const float*)d_in[11];
    const float* W1   = (const float*)d_in[12];
    const float* b1   = (const float*)d_in[13];
    const float* W2   = (const float*)d_in[14];
    const float* b2   = (const float*)d_in[15];
    const float* g1   = (const float*)d_in[16];
    const float* be1  = (const float*)d_in[17];
    const float* g2   = (const float*)d_in[18];
    const float* be2  = (const float*)d_in[19];
    float* out = (float*)d_out;

    // Workspace layout (~135 MB). Aliasing (stream-serialized):
    //   tbuf fp32 (22.3MB) aliases srcB+qB (dead after value/offlg GEMMs)
    //   src2 fp32 (22.3MB) aliases olg    (dead after meta)
    //   meta (44.6MB) aliases h           (h written at FFN1, meta consumed)
    char* wsp = (char*)d_ws;
    unsigned short* srcB = (unsigned short*)wsp; wsp += NT256 * 2;
    unsigned short* qB   = (unsigned short*)wsp; wsp += NT256 * 2;
    float*          tbuf = (float*)srcB;
    __half*         valB = (__half*)wsp;         wsp += NT256 * 2;
    float*          olg  = (float*)wsp;          wsp += (size_t)NTOK * 384 * 4;
    float*          src2 = olg;
    unsigned short* aoB  = (unsigned short*)wsp; wsp += NT256 * 2;
    unsigned short* xB   = (unsigned short*)wsp; wsp += NT256 * 2;
    unsigned short* h    = (unsigned short*)wsp; wsp += (size_t)NTOK * 1024 * 2;
    uint4*          meta = (uint4*)h;
    unsigned short* WvT  = (unsigned short*)wsp; wsp += 256 * 256 * 2;
    unsigned short* WcatT= (unsigned short*)wsp; wsp += 384 * 256 * 2;
    unsigned short* WoT  = (unsigned short*)wsp; wsp += 256 * 256 * 2;
    unsigned short* W1T  = (unsigned short*)wsp; wsp += 1024 * 256 * 2;
    unsigned short* W2T  = (unsigned short*)wsp; wsp += 256 * 1024 * 2;

    const dim3 blk(256);
    const int MB = NTOK / 64;   // 340 row-blocks

    prep_kernel<<<dim3(NT256 / 1024), blk, 0, stream>>>(src, pos, srcB, qB);
    transpose_all_kernel<<<dim3(184), blk, 0, stream>>>(
        Wv, Woff, Wa, Wo, W1, W2, WvT, WcatT, WoT, W1T, W2T);

    // 1. value = src @ Wv + bv  (fp16 out for sampler)
    gemm_as_kernel<false, 2><<<dim3(2, MB), blk, 0, stream>>>(
        srcB, WvT, bv, bv, 1 << 30, valB, NTOK, 256, 256);
    // 2. olg = q @ [Woff|Wa] + [boff|ba]  (fp32, N=384, bias split at 256)
    gemm_as_kernel<false, 0><<<dim3(3, MB), blk, 0, stream>>>(
        qB, WcatT, boff, ba, 256, olg, NTOK, 384, 256);
    // 3. meta: per-point fused softmax/coords -> packed idx+weights
    msda_meta_kernel<<<dim3(NTOK * 128 / 256), blk, 0, stream>>>(olg, meta);
    // 4. sampling gather -> attn_out (bf16)
    msda_sample_kernel<<<dim3(NTOK / 8), blk, 0, stream>>>(valB, meta, aoB);
    // 5. src2 = attn_out @ Wo + bo (fp32, overwrites olg)
    gemm_as_kernel<false, 0><<<dim3(2, MB), blk, 0, stream>>>(
        aoB, WoT, bo, bo, 1 << 30, src2, NTOK, 256, 256);
    // 6. xB = bf16(LN(src + src2))
    ln_kernel<false, false, true><<<dim3(NTOK / 4), blk, 0, stream>>>(
        src, src2, g1, be1, nullptr, xB);
    // 7. h = relu(xB @ W1 + b1) (bf16; overwrites meta region — consumed)
    gemm_as_kernel<true, 1><<<dim3(8, MB), blk, 0, stream>>>(
        xB, W1T, b1, b1, 1 << 30, h, NTOK, 1024, 256);
    // 8. t = h @ W2 + b2 (fp32, K=1024 -> 4 staged chunks; overwrites srcB/qB)
    gemm_as_kernel<false, 0><<<dim3(2, MB), blk, 0, stream>>>(
        h, W2T, b2, b2, 1 << 30, tbuf, NTOK, 256, 1024);
    // 9. out = LN(xB + t)
    ln_kernel<true, true, false><<<dim3(NTOK / 4), blk, 0, stream>>>(
        xB, tbuf, g2, be2, out, nullptr);
}

// Round 7
// 319.198 us; speedup vs baseline: 1.1013x; 1.1013x over previous
//
#include <hip/hip_runtime.h>
#include <hip/hip_fp16.h>
#include <cstddef>
#include <cstdint>

// Problem constants (fixed by reference setup_inputs)
#define DMODEL 256
#define NHEAD  8
#define NLVL   4
#define NPT    4
#define DHEAD  32
#define DFFN   1024
#define SLEN   5440
#define BATCH  4
#define NTOK   (BATCH * SLEN)   // 21760 = 340*64
#define NT256  ((size_t)NTOK * 256)
#define LN_EPS 1e-5f

typedef __attribute__((ext_vector_type(4))) float f32x4;
typedef __attribute__((ext_vector_type(8))) short s16x8;

__device__ __forceinline__ unsigned short f2bf(float f) {
    union { float f; unsigned u; } v; v.f = f;
    unsigned u = v.u;
    u += 0x7FFFu + ((u >> 16) & 1u);   // round-to-nearest-even
    return (unsigned short)(u >> 16);
}
__device__ __forceinline__ float bf2f(unsigned short h) {
    union { unsigned u; float f; } v; v.u = ((unsigned)h) << 16;
    return v.f;
}

// ---------------------------------------------------------------------------
// prep: srcB = bf16(src); qB = bf16(src + pos)
// ---------------------------------------------------------------------------
__global__ __launch_bounds__(256) void prep_kernel(
    const float* __restrict__ src, const float* __restrict__ pos,
    unsigned short* __restrict__ srcB, unsigned short* __restrict__ qB)
{
    const size_t i = ((size_t)blockIdx.x * 256 + threadIdx.x) * 4;
    const float4 s = *(const float4*)(src + i);
    const float4 p = *(const float4*)(pos + i);
    ushort4 sb, qb;
    sb.x = f2bf(s.x); sb.y = f2bf(s.y); sb.z = f2bf(s.z); sb.w = f2bf(s.w);
    qb.x = f2bf(s.x + p.x); qb.y = f2bf(s.y + p.y);
    qb.z = f2bf(s.z + p.z); qb.w = f2bf(s.w + p.w);
    *(ushort4*)(srcB + i) = sb;
    *(ushort4*)(qB + i) = qb;
}

// ---------------------------------------------------------------------------
// All weight transposes in ONE launch. W [K][N] fp32 -> Wt [N][K] bf16.
// Woff and Wa go into ONE concatenated WcatT [384][256] (rows 256.. = Wa).
// ---------------------------------------------------------------------------
__global__ __launch_bounds__(256) void transpose_all_kernel(
    const float* __restrict__ Wv, const float* __restrict__ Woff,
    const float* __restrict__ Wa, const float* __restrict__ Wo,
    const float* __restrict__ W1, const float* __restrict__ W2,
    unsigned short* __restrict__ WvT, unsigned short* __restrict__ WcatT,
    unsigned short* __restrict__ WoT,
    unsigned short* __restrict__ W1T, unsigned short* __restrict__ W2T)
{
    const int bid = blockIdx.x;
    const float* W; unsigned short* Wt; int K, N, t;
    if (bid < 16)       { W = Wv;   Wt = WvT;              K = 256;  N = 256;  t = bid; }
    else if (bid < 32)  { W = Woff; Wt = WcatT;            K = 256;  N = 256;  t = bid - 16; }
    else if (bid < 40)  { W = Wa;   Wt = WcatT + 256*256;  K = 256;  N = 128;  t = bid - 32; }
    else if (bid < 56)  { W = Wo;   Wt = WoT;              K = 256;  N = 256;  t = bid - 40; }
    else if (bid < 120) { W = W1;   Wt = W1T;              K = 256;  N = 1024; t = bid - 56; }
    else                { W = W2;   Wt = W2T;              K = 1024; N = 256;  t = bid - 120; }
    const int ntx = N >> 6;
    const int k0 = (t / ntx) * 64, n0 = (t % ntx) * 64;

    __shared__ float T[64][65];
    const int r  = threadIdx.x >> 4;
    const int c4 = (threadIdx.x & 15) * 4;
    #pragma unroll
    for (int rep = 0; rep < 4; rep++) {
        const int k = rep * 16 + r;
        const float4 v = *(const float4*)(W + (size_t)(k0 + k) * N + n0 + c4);
        T[c4 + 0][k] = v.x; T[c4 + 1][k] = v.y;
        T[c4 + 2][k] = v.z; T[c4 + 3][k] = v.w;
    }
    __syncthreads();
    #pragma unroll
    for (int rep = 0; rep < 4; rep++) {
        const int n = rep * 16 + r;
        ushort4 o;
        o.x = f2bf(T[n][c4 + 0]); o.y = f2bf(T[n][c4 + 1]);
        o.z = f2bf(T[n][c4 + 2]); o.w = f2bf(T[n][c4 + 3]);
        *(ushort4*)(Wt + (size_t)(n0 + n) * K + k0 + c4) = o;
    }
}

// ---------------------------------------------------------------------------
// B-resident march GEMM.  C[m,n] = act(A[m,:].Bt[n,:] + bias[n])
// Block owns COLS output columns; stages its FULL B strip (COLS x KK) into
// padded LDS ONCE (the only barrier), then marches 2 chunks of 64 A-rows:
//   per k-step: A-frag = coalesced direct-global 16B load (16 rows x 64B),
//   B-frag from LDS (stride KK+8 halves -> conflict-free), MFMA, epilogue.
// NO barriers / vmcnt(0) drains in the march; chunk c+1 loads hoist over
// chunk c MFMAs. 4 waves, wave w = rows w*16..+16 of the chunk.
// Grid: (N/COLS, NTOK/128).  OM: 0=f32, 1=bf16, 2=f16.
// ---------------------------------------------------------------------------
template <int KK, int COLS, bool RELU, int OM>
__global__ __launch_bounds__(256, 4) void gemm_mk_kernel(
    const unsigned short* __restrict__ A,
    const unsigned short* __restrict__ Bt,
    const float* __restrict__ bias, const float* __restrict__ bias2,
    int bsplit,
    void* __restrict__ Cout, int N)
{
    constexpr int LDB = KK + 8;   // halves; stride bytes = 2*LDB, 16B-aligned
    __shared__ __align__(16) unsigned short sB[COLS * LDB];

    const int tid  = threadIdx.x;
    const int w    = tid >> 6;
    const int lane = tid & 63;
    const int m16  = lane & 15;
    const int q    = lane >> 4;
    const int col0 = blockIdx.x * COLS;

    // ---- one-time B stage (coalesced: consecutive tid -> consecutive k8) ----
    constexpr int K8  = KK / 8;              // 16B chunks per B row
    constexpr int NCH = COLS * K8 / 256;     // chunks per thread
    #pragma unroll
    for (int c = 0; c < NCH; c++) {
        const int id = c * 256 + tid;
        const int bc = id / K8;
        const int k8 = id - bc * K8;
        *(int4*)&sB[bc * LDB + k8 * 8] =
            *(const int4*)(Bt + (size_t)(col0 + bc) * KK + k8 * 8);
    }
    __syncthreads();   // the ONLY barrier in this kernel

    constexpr int NJ = COLS / 16;

    #pragma unroll
    for (int c = 0; c < 2; c++) {   // march: 2 chunks of 64 rows
        const int rowb = (blockIdx.y * 2 + c) * 64 + w * 16;
        const unsigned short* ap = A + (size_t)(rowb + m16) * KK + q * 8;

        f32x4 acc[NJ];
        #pragma unroll
        for (int j = 0; j < NJ; j++) acc[j] = (f32x4){0.f, 0.f, 0.f, 0.f};

        #pragma unroll 8
        for (int ks = 0; ks < KK / 32; ks++) {
            const s16x8 af = *(const s16x8*)(ap + ks * 32);
            #pragma unroll
            for (int j = 0; j < NJ; j++) {
                const s16x8 bf = *(const s16x8*)
                    &sB[(j * 16 + m16) * LDB + ks * 32 + q * 8];
                acc[j] = __builtin_amdgcn_mfma_f32_16x16x32_bf16(
                    af, bf, acc[j], 0, 0, 0);
            }
        }

        // epilogue: D layout col=lane&15, row=(lane>>4)*4+reg (m89/m91-verified)
        #pragma unroll
        for (int j = 0; j < NJ; j++) {
            const int col = col0 + j * 16 + m16;
            const float bcol = (col < bsplit) ? bias[col] : bias2[col - bsplit];
            #pragma unroll
            for (int r = 0; r < 4; r++) {
                const int row = rowb + q * 4 + r;
                float v = acc[j][r] + bcol;
                if (RELU) v = fmaxf(v, 0.f);
                if (OM == 1)
                    ((unsigned short*)Cout)[(size_t)row * N + col] = f2bf(v);
                else if (OM == 2)
                    ((__half*)Cout)[(size_t)row * N + col] = __float2half(v);
                else
                    ((float*)Cout)[(size_t)row * N + col] = v;
            }
        }
    }
}

// ---------------------------------------------------------------------------
// MSDA meta kernel: one thread per (bq, h, p). Softmax via 16-lane shfl.
// Reads fused olg [NTOK][384] (cols 0..255 = offsets, 256..383 = logits).
// meta[bq][p][h] = uint4 { idx0|idx1<<16, idx2|idx3<<16, half2(w0,w1), half2(w2,w3) }
// ---------------------------------------------------------------------------
__global__ __launch_bounds__(256) void msda_meta_kernel(
    const float* __restrict__ olg, uint4* __restrict__ meta)
{
    const int t  = blockIdx.x * 256 + threadIdx.x;   // [0, NTOK*128)
    const int p  = t & 15;
    const int h  = (t >> 4) & 7;
    const int bq = t >> 7;
    const int b  = bq / SLEN;
    const int q  = bq - b * SLEN;

    int rem, Wq;
    if (q < 4096)      { rem = q;        Wq = 64; }
    else if (q < 5120) { rem = q - 4096; Wq = 32; }
    else if (q < 5376) { rem = q - 5120; Wq = 16; }
    else               { rem = q - 5376; Wq = 8;  }
    const int gy = rem / Wq;
    const int gx = rem - gy * Wq;
    const float ref_x = (gx + 0.5f) / (float)Wq;
    const float ref_y = (gy + 0.5f) / (float)Wq;

    const float lg = olg[(size_t)bq * 384 + 256 + h * 16 + p];
    float mx = lg;
    #pragma unroll
    for (int m = 1; m < 16; m <<= 1) mx = fmaxf(mx, __shfl_xor(mx, m));
    const float e = expf(lg - mx);
    float s = e;
    #pragma unroll
    for (int m = 1; m < 16; m <<= 1) s += __shfl_xor(s, m);
    const float aw = e / s;

    const float2 o2 = *(const float2*)(olg + (size_t)bq * 384 + h * 32 + 2 * p);

    const int l = p >> 2;
    constexpr int LW[4] = {64, 32, 16, 8};
    constexpr int LS[4] = {0, 4096, 5120, 5376};
    const int Wl = LW[l];
    const float fW = (float)Wl;

    // mirror reference arithmetic exactly: (ref + off/W)*W - 0.5
    const float X = (ref_x + o2.x / fW) * fW - 0.5f;
    const float Y = (ref_y + o2.y / fW) * fW - 0.5f;
    const float x0f = floorf(X), y0f = floorf(Y);
    const float fx = X - x0f, fy = Y - y0f;
    const int x0 = (int)x0f, y0 = (int)y0f;

    unsigned idx[4]; __half hw[4];
    #pragma unroll
    for (int dy = 0; dy < 2; dy++) {
        const int yi = y0 + dy;
        const float wy = dy ? fy : (1.f - fy);
        const bool vy = (yi >= 0) && (yi < Wl);
        const int yc = min(max(yi, 0), Wl - 1);
        #pragma unroll
        for (int dx = 0; dx < 2; dx++) {
            const int xi = x0 + dx;
            const float wx = dx ? fx : (1.f - fx);
            const bool vx = (xi >= 0) && (xi < Wl);
            const int xc = min(max(xi, 0), Wl - 1);
            const int c = dy * 2 + dx;
            idx[c] = (unsigned)(LS[l] + yc * Wl + xc);   // < 5440, fits u16
            hw[c] = __float2half((vx && vy) ? (aw * wx * wy) : 0.f);
        }
    }
    union { __half2 h2; unsigned u; } pk0, pk1;
    pk0.h2 = __halves2half2(hw[0], hw[1]);
    pk1.h2 = __halves2half2(hw[2], hw[3]);
    uint4 m;
    m.x = idx[0] | (idx[1] << 16);
    m.y = idx[2] | (idx[3] << 16);
    m.z = pk0.u;
    m.w = pk1.u;
    meta[((size_t)bq * 16 + p) * 8 + h] = m;
}

// ---------------------------------------------------------------------------
// MSDA gather: block = 8 tokens; lane = 8 channels (16B) of one head.
// ---------------------------------------------------------------------------
__global__ __launch_bounds__(256) void msda_sample_kernel(
    const __half* __restrict__ value, const uint4* __restrict__ meta,
    unsigned short* __restrict__ out)
{
    const int tid = threadIdx.x;
    const int sub = tid & 3;
    const int h   = (tid >> 2) & 7;
    const int t8  = tid >> 5;
    const int bq  = blockIdx.x * 8 + t8;
    const int b   = (blockIdx.x * 8) / SLEN;     // uniform per block (5440%8==0)

    const char* vb = (const char*)value + (size_t)b * SLEN * 512;
    const unsigned laneoff = (unsigned)(h * 64 + sub * 16);
    const uint4* metap = meta + (size_t)bq * 128 + h;   // index with p*8

    __half2 acc[4][4];
    #pragma unroll
    for (int i = 0; i < 4; i++)
        #pragma unroll
        for (int k = 0; k < 4; k++)
            acc[i][k] = __float2half2_rn(0.f);

    for (int g = 0; g < 4; g++) {
        #pragma unroll
        for (int pp = 0; pp < 4; pp++) {
            const int p = g * 4 + pp;
            const uint4 m = metap[p * 8];
            const unsigned a0 = ((m.x & 0xFFFFu) << 9) + laneoff;
            const unsigned a1 = ((m.x >> 16) << 9) + laneoff;
            const unsigned a2 = ((m.y & 0xFFFFu) << 9) + laneoff;
            const unsigned a3 = ((m.y >> 16) << 9) + laneoff;
            const int4 v0 = *(const int4*)(vb + a0);
            const int4 v1 = *(const int4*)(vb + a1);
            const int4 v2 = *(const int4*)(vb + a2);
            const int4 v3 = *(const int4*)(vb + a3);
            union { unsigned u; __half2 h2; } wz, ww;
            wz.u = m.z; ww.u = m.w;
            const __half2 ws0 = __half2half2(__low2half(wz.h2));
            const __half2 ws1 = __half2half2(__high2half(wz.h2));
            const __half2 ws2 = __half2half2(__low2half(ww.h2));
            const __half2 ws3 = __half2half2(__high2half(ww.h2));
            const __half2* p0 = (const __half2*)&v0;
            const __half2* p1 = (const __half2*)&v1;
            const __half2* p2 = (const __half2*)&v2;
            const __half2* p3 = (const __half2*)&v3;
            #pragma unroll
            for (int k = 0; k < 4; k++) {
                acc[pp][k] = __hfma2(ws0, p0[k], acc[pp][k]);
                acc[pp][k] = __hfma2(ws1, p1[k], acc[pp][k]);
                acc[pp][k] = __hfma2(ws2, p2[k], acc[pp][k]);
                acc[pp][k] = __hfma2(ws3, p3[k], acc[pp][k]);
            }
        }
    }

    uint4 o;
    unsigned* ou = &o.x;
    #pragma unroll
    for (int k = 0; k < 4; k++) {
        float2 s = {0.f, 0.f};
        #pragma unroll
        for (int i = 0; i < 4; i++) {
            const float2 f = __half22float2(acc[i][k]);
            s.x += f.x; s.y += f.y;
        }
        ou[k] = (unsigned)f2bf(s.x) | ((unsigned)f2bf(s.y) << 16);
    }
    *(uint4*)(out + (size_t)bq * 256 + h * 32 + sub * 8) = o;
}

// ---------------------------------------------------------------------------
// Fused residual-add + LayerNorm. One wave per row, 4 rows/block.
// X1B/X2B: inputs bf16 (else fp32). WF: write fp32 out. WB: write bf16 out.
// ---------------------------------------------------------------------------
template <bool X1B, bool X2B, bool WF, bool WB>
__global__ __launch_bounds__(256) void ln_kernel(
    const void* __restrict__ x1, const void* __restrict__ x2,
    const float* __restrict__ g, const float* __restrict__ be,
    float* __restrict__ outf, unsigned short* __restrict__ outb)
{
    const int lane = threadIdx.x & 63;
    const int wid  = threadIdx.x >> 6;
    const size_t row  = (size_t)blockIdx.x * 4 + wid;
    const size_t base = row * 256 + lane * 4;

    float a0, a1, a2, a3, b0, b1, b2, b3;
    if (X1B) {
        const ushort4 a = *(const ushort4*)((const unsigned short*)x1 + base);
        a0 = bf2f(a.x); a1 = bf2f(a.y); a2 = bf2f(a.z); a3 = bf2f(a.w);
    } else {
        const float4 a = *(const float4*)((const float*)x1 + base);
        a0 = a.x; a1 = a.y; a2 = a.z; a3 = a.w;
    }
    if (X2B) {
        const ushort4 b = *(const ushort4*)((const unsigned short*)x2 + base);
        b0 = bf2f(b.x); b1 = bf2f(b.y); b2 = bf2f(b.z); b3 = bf2f(b.w);
    } else {
        const float4 b = *(const float4*)((const float*)x2 + base);
        b0 = b.x; b1 = b.y; b2 = b.z; b3 = b.w;
    }
    const float v0 = a0 + b0, v1 = a1 + b1, v2 = a2 + b2, v3 = a3 + b3;

    float s  = v0 + v1 + v2 + v3;
    float s2 = v0 * v0 + v1 * v1 + v2 * v2 + v3 * v3;
    #pragma unroll
    for (int o = 32; o > 0; o >>= 1) {
        s  += __shfl_xor(s, o);
        s2 += __shfl_xor(s2, o);
    }
    const float mu  = s * (1.f / 256.f);
    const float var = s2 * (1.f / 256.f) - mu * mu;
    const float r   = rsqrtf(var + LN_EPS);

    const float4 gv = *(const float4*)(g  + lane * 4);
    const float4 bv = *(const float4*)(be + lane * 4);
    float4 o4;
    o4.x = (v0 - mu) * r * gv.x + bv.x;
    o4.y = (v1 - mu) * r * gv.y + bv.y;
    o4.z = (v2 - mu) * r * gv.z + bv.z;
    o4.w = (v3 - mu) * r * gv.w + bv.w;
    if (WF) *(float4*)(outf + base) = o4;
    if (WB) {
        ushort4 ob;
        ob.x = f2bf(o4.x); ob.y = f2bf(o4.y); ob.z = f2bf(o4.z); ob.w = f2bf(o4.w);
        *(ushort4*)(outb + base) = ob;
    }
}

// ---------------------------------------------------------------------------
extern "C" void kernel_launch(void* const* d_in, const int* in_sizes, int n_in,
                              void* d_out, int out_size, void* d_ws, size_t ws_size,
                              hipStream_t stream)
{
    const float* src  = (const float*)d_in[0];
    const float* pos  = (const float*)d_in[1];
    const float* Wv   = (const float*)d_in[4];
    const float* bv   = (const float*)d_in[5];
    const float* Woff = (const float*)d_in[6];
    const float* boff = (const float*)d_in[7];
    const float* Wa   = (const float*)d_in[8];
    const float* ba   = (const float*)d_in[9];
    const float* Wo   = (const float*)d_in[10];
    const float* bo   = (const float*)d_in[11];
    const float* W1   = (const float*)d_in[12];
    const float* b1   = (const float*)d_in[13];
    const float* W2   = (const float*)d_in[14];
    const float* b2   = (const float*)d_in[15];
    const float* g1   = (const float*)d_in[16];
    const float* be1  = (const float*)d_in[17];
    const float* g2   = (const float*)d_in[18];
    const float* be2  = (const float*)d_in[19];
    float* out = (float*)d_out;

    // Workspace layout. Aliasing (stream-serialized):
    //   tbufB bf16 (11.1MB) aliases srcB (dead after value GEMM)
    //   src2 fp32 (22.3MB)  aliases olg  (dead after meta)
    //   meta (44.6MB)       aliases h    (h written at FFN1, meta consumed)
    char* wsp = (char*)d_ws;
    unsigned short* srcB = (unsigned short*)wsp; wsp += NT256 * 2;
    unsigned short* qB   = (unsigned short*)wsp; wsp += NT256 * 2;
    unsigned short* tbufB = srcB;
    __half*         valB = (__half*)wsp;         wsp += NT256 * 2;
    float*          olg  = (float*)wsp;          wsp += (size_t)NTOK * 384 * 4;
    float*          src2 = olg;
    unsigned short* aoB  = (unsigned short*)wsp; wsp += NT256 * 2;
    unsigned short* xB   = (unsigned short*)wsp; wsp += NT256 * 2;
    unsigned short* h    = (unsigned short*)wsp; wsp += (size_t)NTOK * 1024 * 2;
    uint4*          meta = (uint4*)h;
    unsigned short* WvT  = (unsigned short*)wsp; wsp += 256 * 256 * 2;
    unsigned short* WcatT= (unsigned short*)wsp; wsp += 384 * 256 * 2;
    unsigned short* WoT  = (unsigned short*)wsp; wsp += 256 * 256 * 2;
    unsigned short* W1T  = (unsigned short*)wsp; wsp += 1024 * 256 * 2;
    unsigned short* W2T  = (unsigned short*)wsp; wsp += 256 * 1024 * 2;

    const dim3 blk(256);
    const int GY = NTOK / 128;   // 170 (each block marches 2x64 rows)

    prep_kernel<<<dim3(NT256 / 1024), blk, 0, stream>>>(src, pos, srcB, qB);
    transpose_all_kernel<<<dim3(184), blk, 0, stream>>>(
        Wv, Woff, Wa, Wo, W1, W2, WvT, WcatT, WoT, W1T, W2T);

    // 1. value = src @ Wv + bv  (fp16 out for sampler)
    gemm_mk_kernel<256, 64, false, 2><<<dim3(4, GY), blk, 0, stream>>>(
        srcB, WvT, bv, bv, 1 << 30, valB, 256);
    // 2. olg = q @ [Woff|Wa] + [boff|ba]  (fp32, N=384, bias split at 256)
    gemm_mk_kernel<256, 64, false, 0><<<dim3(6, GY), blk, 0, stream>>>(
        qB, WcatT, boff, ba, 256, olg, 384);
    // 3. meta: per-point fused softmax/coords -> packed idx+weights
    msda_meta_kernel<<<dim3(NTOK * 128 / 256), blk, 0, stream>>>(olg, meta);
    // 4. sampling gather -> attn_out (bf16)
    msda_sample_kernel<<<dim3(NTOK / 8), blk, 0, stream>>>(valB, meta, aoB);
    // 5. src2 = attn_out @ Wo + bo (fp32, overwrites olg)
    gemm_mk_kernel<256, 64, false, 0><<<dim3(4, GY), blk, 0, stream>>>(
        aoB, WoT, bo, bo, 1 << 30, src2, 256);
    // 6. xB = bf16(LN(src + src2))
    ln_kernel<false, false, false, true><<<dim3(NTOK / 4), blk, 0, stream>>>(
        src, src2, g1, be1, nullptr, xB);
    // 7. h = relu(xB @ W1 + b1) (bf16; overwrites meta region — consumed)
    gemm_mk_kernel<256, 64, true, 1><<<dim3(16, GY), blk, 0, stream>>>(
        xB, W1T, b1, b1, 1 << 30, h, 1024);
    // 8. t = h @ W2 + b2 (bf16; K=1024, 32-col strips, 65KB LDS -> 2 blk/CU)
    gemm_mk_kernel<1024, 32, false, 1><<<dim3(8, GY), blk, 0, stream>>>(
        h, W2T, b2, b2, 1 << 30, tbufB, 256);
    // 9. out = LN(xB + t)
    ln_kernel<true, true, true, false><<<dim3(NTOK / 4), blk, 0, stream>>>(
        xB, tbufB, g2, be2, out, nullptr);
}

// Round 8
// 302.878 us; speedup vs baseline: 1.1606x; 1.0539x over previous
//
#include <hip/hip_runtime.h>
#include <hip/hip_fp16.h>
#include <cstddef>
#include <cstdint>

// Problem constants (fixed by reference setup_inputs)
#define DMODEL 256
#define NHEAD  8
#define NLVL   4
#define NPT    4
#define DHEAD  32
#define DFFN   1024
#define SLEN   5440
#define BATCH  4
#define NTOK   (BATCH * SLEN)   // 21760 = 340*64
#define NT256  ((size_t)NTOK * 256)
#define GYR    170              // row-groups of 128 rows
#define GYP    176              // padded to multiple of 8 for XCD swizzle
#define LN_EPS 1e-5f

typedef __attribute__((ext_vector_type(4))) float f32x4;
typedef __attribute__((ext_vector_type(8))) short s16x8;

__device__ __forceinline__ unsigned short f2bf(float f) {
    union { float f; unsigned u; } v; v.f = f;
    unsigned u = v.u;
    u += 0x7FFFu + ((u >> 16) & 1u);   // round-to-nearest-even
    return (unsigned short)(u >> 16);
}
__device__ __forceinline__ float bf2f(unsigned short h) {
    union { unsigned u; float f; } v; v.u = ((unsigned)h) << 16;
    return v.f;
}

// ---------------------------------------------------------------------------
// prep: srcB = bf16(src); qB = bf16(src + pos)
// ---------------------------------------------------------------------------
__global__ __launch_bounds__(256) void prep_kernel(
    const float* __restrict__ src, const float* __restrict__ pos,
    unsigned short* __restrict__ srcB, unsigned short* __restrict__ qB)
{
    const size_t i = ((size_t)blockIdx.x * 256 + threadIdx.x) * 4;
    const float4 s = *(const float4*)(src + i);
    const float4 p = *(const float4*)(pos + i);
    ushort4 sb, qb;
    sb.x = f2bf(s.x); sb.y = f2bf(s.y); sb.z = f2bf(s.z); sb.w = f2bf(s.w);
    qb.x = f2bf(s.x + p.x); qb.y = f2bf(s.y + p.y);
    qb.z = f2bf(s.z + p.z); qb.w = f2bf(s.w + p.w);
    *(ushort4*)(srcB + i) = sb;
    *(ushort4*)(qB + i) = qb;
}

// ---------------------------------------------------------------------------
// All weight transposes in ONE launch. W [K][N] fp32 -> Wt [N][K] bf16.
// Woff and Wa go into ONE concatenated WcatT [384][256] (rows 256.. = Wa).
// ---------------------------------------------------------------------------
__global__ __launch_bounds__(256) void transpose_all_kernel(
    const float* __restrict__ Wv, const float* __restrict__ Woff,
    const float* __restrict__ Wa, const float* __restrict__ Wo,
    const float* __restrict__ W1, const float* __restrict__ W2,
    unsigned short* __restrict__ WvT, unsigned short* __restrict__ WcatT,
    unsigned short* __restrict__ WoT,
    unsigned short* __restrict__ W1T, unsigned short* __restrict__ W2T)
{
    const int bid = blockIdx.x;
    const float* W; unsigned short* Wt; int K, N, t;
    if (bid < 16)       { W = Wv;   Wt = WvT;              K = 256;  N = 256;  t = bid; }
    else if (bid < 32)  { W = Woff; Wt = WcatT;            K = 256;  N = 256;  t = bid - 16; }
    else if (bid < 40)  { W = Wa;   Wt = WcatT + 256*256;  K = 256;  N = 128;  t = bid - 32; }
    else if (bid < 56)  { W = Wo;   Wt = WoT;              K = 256;  N = 256;  t = bid - 40; }
    else if (bid < 120) { W = W1;   Wt = W1T;              K = 256;  N = 1024; t = bid - 56; }
    else                { W = W2;   Wt = W2T;              K = 1024; N = 256;  t = bid - 120; }
    const int ntx = N >> 6;
    const int k0 = (t / ntx) * 64, n0 = (t % ntx) * 64;

    __shared__ float T[64][65];
    const int r  = threadIdx.x >> 4;
    const int c4 = (threadIdx.x & 15) * 4;
    #pragma unroll
    for (int rep = 0; rep < 4; rep++) {
        const int k = rep * 16 + r;
        const float4 v = *(const float4*)(W + (size_t)(k0 + k) * N + n0 + c4);
        T[c4 + 0][k] = v.x; T[c4 + 1][k] = v.y;
        T[c4 + 2][k] = v.z; T[c4 + 3][k] = v.w;
    }
    __syncthreads();
    #pragma unroll
    for (int rep = 0; rep < 4; rep++) {
        const int n = rep * 16 + r;
        ushort4 o;
        o.x = f2bf(T[n][c4 + 0]); o.y = f2bf(T[n][c4 + 1]);
        o.z = f2bf(T[n][c4 + 2]); o.w = f2bf(T[n][c4 + 3]);
        *(ushort4*)(Wt + (size_t)(n0 + n) * K + k0 + c4) = o;
    }
}

// ---------------------------------------------------------------------------
// B-resident march GEMM with XCD-aware swizzle.
// Block owns COLS output columns; stages its FULL B strip (COLS x KK) into
// padded LDS ONCE (the only barrier), then marches 2 chunks of 64 A-rows.
// 1D grid, NX*GYP blocks. Decode maps ALL NX column strips of row-group y
// onto XCD y%8 (assuming round-robin lin%8 -> XCD), so each row-group's A is
// fetched into exactly ONE per-XCD L2 and reused by all its strips.
// OM: 0=f32, 1=bf16, 2=f16.
// ---------------------------------------------------------------------------
template <int KK, int COLS, int NX, bool RELU, int OM>
__global__ __launch_bounds__(256, 4) void gemm_mk_kernel(
    const unsigned short* __restrict__ A,
    const unsigned short* __restrict__ Bt,
    const float* __restrict__ bias, const float* __restrict__ bias2,
    int bsplit,
    void* __restrict__ Cout, int N)
{
    // XCD swizzle decode: lin = c8 + 8*(bx + NX*y8); y = y8*8 + c8
    const int lin = blockIdx.x;
    const int c8  = lin & 7;
    const int rr  = lin >> 3;
    const int bx  = rr % NX;
    const int yy  = (rr / NX) * 8 + c8;
    if (yy >= GYR) return;              // uniform per block: safe before barrier

    constexpr int LDB = KK + 8;   // halves; stride bytes = 2*LDB, 16B-aligned
    __shared__ __align__(16) unsigned short sB[COLS * LDB];

    const int tid  = threadIdx.x;
    const int w    = tid >> 6;
    const int lane = tid & 63;
    const int m16  = lane & 15;
    const int q    = lane >> 4;
    const int col0 = bx * COLS;

    // ---- one-time B stage (coalesced: consecutive tid -> consecutive k8) ----
    constexpr int K8  = KK / 8;              // 16B chunks per B row
    constexpr int NCH = COLS * K8 / 256;     // chunks per thread
    #pragma unroll
    for (int c = 0; c < NCH; c++) {
        const int id = c * 256 + tid;
        const int bc = id / K8;
        const int k8 = id - bc * K8;
        *(int4*)&sB[bc * LDB + k8 * 8] =
            *(const int4*)(Bt + (size_t)(col0 + bc) * KK + k8 * 8);
    }
    __syncthreads();   // the ONLY barrier in this kernel

    constexpr int NJ = COLS / 16;

    #pragma unroll
    for (int c = 0; c < 2; c++) {   // march: 2 chunks of 64 rows
        const int rowb = (yy * 2 + c) * 64 + w * 16;
        const unsigned short* ap = A + (size_t)(rowb + m16) * KK + q * 8;

        f32x4 acc[NJ];
        #pragma unroll
        for (int j = 0; j < NJ; j++) acc[j] = (f32x4){0.f, 0.f, 0.f, 0.f};

        #pragma unroll 8
        for (int ks = 0; ks < KK / 32; ks++) {
            const s16x8 af = *(const s16x8*)(ap + ks * 32);
            #pragma unroll
            for (int j = 0; j < NJ; j++) {
                const s16x8 bf = *(const s16x8*)
                    &sB[(j * 16 + m16) * LDB + ks * 32 + q * 8];
                acc[j] = __builtin_amdgcn_mfma_f32_16x16x32_bf16(
                    af, bf, acc[j], 0, 0, 0);
            }
        }

        // epilogue: D layout col=lane&15, row=(lane>>4)*4+reg (m89/m91-verified)
        #pragma unroll
        for (int j = 0; j < NJ; j++) {
            const int col = col0 + j * 16 + m16;
            const float bcol = (col < bsplit) ? bias[col] : bias2[col - bsplit];
            #pragma unroll
            for (int r = 0; r < 4; r++) {
                const int row = rowb + q * 4 + r;
                float v = acc[j][r] + bcol;
                if (RELU) v = fmaxf(v, 0.f);
                if (OM == 1)
                    ((unsigned short*)Cout)[(size_t)row * N + col] = f2bf(v);
                else if (OM == 2)
                    ((__half*)Cout)[(size_t)row * N + col] = __float2half(v);
                else
                    ((float*)Cout)[(size_t)row * N + col] = v;
            }
        }
    }
}

// ---------------------------------------------------------------------------
// MSDA meta kernel: one thread per (bq, h, p). Softmax via 16-lane shfl.
// Reads fused olg [NTOK][384] (cols 0..255 = offsets, 256..383 = logits).
// meta[bq][p][h] = uint4 { idx0|idx1<<16, idx2|idx3<<16, half2(w0,w1), half2(w2,w3) }
// ---------------------------------------------------------------------------
__global__ __launch_bounds__(256) void msda_meta_kernel(
    const float* __restrict__ olg, uint4* __restrict__ meta)
{
    const int t  = blockIdx.x * 256 + threadIdx.x;   // [0, NTOK*128)
    const int p  = t & 15;
    const int h  = (t >> 4) & 7;
    const int bq = t >> 7;
    const int b  = bq / SLEN;
    const int q  = bq - b * SLEN;

    int rem, Wq;
    if (q < 4096)      { rem = q;        Wq = 64; }
    else if (q < 5120) { rem = q - 4096; Wq = 32; }
    else if (q < 5376) { rem = q - 5120; Wq = 16; }
    else               { rem = q - 5376; Wq = 8;  }
    const int gy = rem / Wq;
    const int gx = rem - gy * Wq;
    const float ref_x = (gx + 0.5f) / (float)Wq;
    const float ref_y = (gy + 0.5f) / (float)Wq;

    const float lg = olg[(size_t)bq * 384 + 256 + h * 16 + p];
    float mx = lg;
    #pragma unroll
    for (int m = 1; m < 16; m <<= 1) mx = fmaxf(mx, __shfl_xor(mx, m));
    const float e = expf(lg - mx);
    float s = e;
    #pragma unroll
    for (int m = 1; m < 16; m <<= 1) s += __shfl_xor(s, m);
    const float aw = e / s;

    const float2 o2 = *(const float2*)(olg + (size_t)bq * 384 + h * 32 + 2 * p);

    const int l = p >> 2;
    constexpr int LW[4] = {64, 32, 16, 8};
    constexpr int LS[4] = {0, 4096, 5120, 5376};
    const int Wl = LW[l];
    const float fW = (float)Wl;

    // mirror reference arithmetic exactly: (ref + off/W)*W - 0.5
    const float X = (ref_x + o2.x / fW) * fW - 0.5f;
    const float Y = (ref_y + o2.y / fW) * fW - 0.5f;
    const float x0f = floorf(X), y0f = floorf(Y);
    const float fx = X - x0f, fy = Y - y0f;
    const int x0 = (int)x0f, y0 = (int)y0f;

    unsigned idx[4]; __half hw[4];
    #pragma unroll
    for (int dy = 0; dy < 2; dy++) {
        const int yi = y0 + dy;
        const float wy = dy ? fy : (1.f - fy);
        const bool vy = (yi >= 0) && (yi < Wl);
        const int yc = min(max(yi, 0), Wl - 1);
        #pragma unroll
        for (int dx = 0; dx < 2; dx++) {
            const int xi = x0 + dx;
            const float wx = dx ? fx : (1.f - fx);
            const bool vx = (xi >= 0) && (xi < Wl);
            const int xc = min(max(xi, 0), Wl - 1);
            const int c = dy * 2 + dx;
            idx[c] = (unsigned)(LS[l] + yc * Wl + xc);   // < 5440, fits u16
            hw[c] = __float2half((vx && vy) ? (aw * wx * wy) : 0.f);
        }
    }
    union { __half2 h2; unsigned u; } pk0, pk1;
    pk0.h2 = __halves2half2(hw[0], hw[1]);
    pk1.h2 = __halves2half2(hw[2], hw[3]);
    uint4 m;
    m.x = idx[0] | (idx[1] << 16);
    m.y = idx[2] | (idx[3] << 16);
    m.z = pk0.u;
    m.w = pk1.u;
    meta[((size_t)bq * 16 + p) * 8 + h] = m;
}

// ---------------------------------------------------------------------------
// MSDA gather: block = 8 tokens; lane = 8 channels (16B) of one head.
// XCD swizzle: batch b's 680 blocks -> XCD pair {2b, 2b+1} (lin%8 -> XCD
// heuristic), so each batch's 2.78 MB value plane is L2-resident.
// ---------------------------------------------------------------------------
__global__ __launch_bounds__(256) void msda_sample_kernel(
    const __half* __restrict__ value, const uint4* __restrict__ meta,
    unsigned short* __restrict__ out)
{
    const int lin = blockIdx.x;          // 0..2719
    const int c8  = lin & 7;
    const int rr  = lin >> 3;            // 0..339
    const int b   = c8 >> 1;             // batch -> XCD pair
    const int i8  = (c8 & 1) + 2 * rr;   // 0..679: block within batch

    const int tid = threadIdx.x;
    const int sub = tid & 3;
    const int h   = (tid >> 2) & 7;
    const int t8  = tid >> 5;
    const int bq  = b * SLEN + i8 * 8 + t8;

    const char* vb = (const char*)value + (size_t)b * SLEN * 512;
    const unsigned laneoff = (unsigned)(h * 64 + sub * 16);
    const uint4* metap = meta + (size_t)bq * 128 + h;   // index with p*8

    __half2 acc[4][4];
    #pragma unroll
    for (int i = 0; i < 4; i++)
        #pragma unroll
        for (int k = 0; k < 4; k++)
            acc[i][k] = __float2half2_rn(0.f);

    for (int g = 0; g < 4; g++) {
        #pragma unroll
        for (int pp = 0; pp < 4; pp++) {
            const int p = g * 4 + pp;
            const uint4 m = metap[p * 8];
            const unsigned a0 = ((m.x & 0xFFFFu) << 9) + laneoff;
            const unsigned a1 = ((m.x >> 16) << 9) + laneoff;
            const unsigned a2 = ((m.y & 0xFFFFu) << 9) + laneoff;
            const unsigned a3 = ((m.y >> 16) << 9) + laneoff;
            const int4 v0 = *(const int4*)(vb + a0);
            const int4 v1 = *(const int4*)(vb + a1);
            const int4 v2 = *(const int4*)(vb + a2);
            const int4 v3 = *(const int4*)(vb + a3);
            union { unsigned u; __half2 h2; } wz, ww;
            wz.u = m.z; ww.u = m.w;
            const __half2 ws0 = __half2half2(__low2half(wz.h2));
            const __half2 ws1 = __half2half2(__high2half(wz.h2));
            const __half2 ws2 = __half2half2(__low2half(ww.h2));
            const __half2 ws3 = __half2half2(__high2half(ww.h2));
            const __half2* p0 = (const __half2*)&v0;
            const __half2* p1 = (const __half2*)&v1;
            const __half2* p2 = (const __half2*)&v2;
            const __half2* p3 = (const __half2*)&v3;
            #pragma unroll
            for (int k = 0; k < 4; k++) {
                acc[pp][k] = __hfma2(ws0, p0[k], acc[pp][k]);
                acc[pp][k] = __hfma2(ws1, p1[k], acc[pp][k]);
                acc[pp][k] = __hfma2(ws2, p2[k], acc[pp][k]);
                acc[pp][k] = __hfma2(ws3, p3[k], acc[pp][k]);
            }
        }
    }

    uint4 o;
    unsigned* ou = &o.x;
    #pragma unroll
    for (int k = 0; k < 4; k++) {
        float2 s = {0.f, 0.f};
        #pragma unroll
        for (int i = 0; i < 4; i++) {
            const float2 f = __half22float2(acc[i][k]);
            s.x += f.x; s.y += f.y;
        }
        ou[k] = (unsigned)f2bf(s.x) | ((unsigned)f2bf(s.y) << 16);
    }
    *(uint4*)(out + (size_t)bq * 256 + h * 32 + sub * 8) = o;
}

// ---------------------------------------------------------------------------
// Fused residual-add + LayerNorm. One wave per row, 4 rows/block.
// X1B/X2B: inputs bf16 (else fp32). WF: write fp32 out. WB: write bf16 out.
// ---------------------------------------------------------------------------
template <bool X1B, bool X2B, bool WF, bool WB>
__global__ __launch_bounds__(256) void ln_kernel(
    const void* __restrict__ x1, const void* __restrict__ x2,
    const float* __restrict__ g, const float* __restrict__ be,
    float* __restrict__ outf, unsigned short* __restrict__ outb)
{
    const int lane = threadIdx.x & 63;
    const int wid  = threadIdx.x >> 6;
    const size_t row  = (size_t)blockIdx.x * 4 + wid;
    const size_t base = row * 256 + lane * 4;

    float a0, a1, a2, a3, b0, b1, b2, b3;
    if (X1B) {
        const ushort4 a = *(const ushort4*)((const unsigned short*)x1 + base);
        a0 = bf2f(a.x); a1 = bf2f(a.y); a2 = bf2f(a.z); a3 = bf2f(a.w);
    } else {
        const float4 a = *(const float4*)((const float*)x1 + base);
        a0 = a.x; a1 = a.y; a2 = a.z; a3 = a.w;
    }
    if (X2B) {
        const ushort4 b = *(const ushort4*)((const unsigned short*)x2 + base);
        b0 = bf2f(b.x); b1 = bf2f(b.y); b2 = bf2f(b.z); b3 = bf2f(b.w);
    } else {
        const float4 b = *(const float4*)((const float*)x2 + base);
        b0 = b.x; b1 = b.y; b2 = b.z; b3 = b.w;
    }
    const float v0 = a0 + b0, v1 = a1 + b1, v2 = a2 + b2, v3 = a3 + b3;

    float s  = v0 + v1 + v2 + v3;
    float s2 = v0 * v0 + v1 * v1 + v2 * v2 + v3 * v3;
    #pragma unroll
    for (int o = 32; o > 0; o >>= 1) {
        s  += __shfl_xor(s, o);
        s2 += __shfl_xor(s2, o);
    }
    const float mu  = s * (1.f / 256.f);
    const float var = s2 * (1.f / 256.f) - mu * mu;
    const float r   = rsqrtf(var + LN_EPS);

    const float4 gv = *(const float4*)(g  + lane * 4);
    const float4 bv = *(const float4*)(be + lane * 4);
    float4 o4;
    o4.x = (v0 - mu) * r * gv.x + bv.x;
    o4.y = (v1 - mu) * r * gv.y + bv.y;
    o4.z = (v2 - mu) * r * gv.z + bv.z;
    o4.w = (v3 - mu) * r * gv.w + bv.w;
    if (WF) *(float4*)(outf + base) = o4;
    if (WB) {
        ushort4 ob;
        ob.x = f2bf(o4.x); ob.y = f2bf(o4.y); ob.z = f2bf(o4.z); ob.w = f2bf(o4.w);
        *(ushort4*)(outb + base) = ob;
    }
}

// ---------------------------------------------------------------------------
extern "C" void kernel_launch(void* const* d_in, const int* in_sizes, int n_in,
                              void* d_out, int out_size, void* d_ws, size_t ws_size,
                              hipStream_t stream)
{
    const float* src  = (const float*)d_in[0];
    const float* pos  = (const float*)d_in[1];
    const float* Wv   = (const float*)d_in[4];
    const float* bv   = (const float*)d_in[5];
    const float* Woff = (const float*)d_in[6];
    const float* boff = (const float*)d_in[7];
    const float* Wa   = (const float*)d_in[8];
    const float* ba   = (const float*)d_in[9];
    const float* Wo   = (const float*)d_in[10];
    const float* bo   = (const float*)d_in[11];
    const float* W1   = (const float*)d_in[12];
    const float* b1   = (const float*)d_in[13];
    const float* W2   = (const float*)d_in[14];
    const float* b2   = (const float*)d_in[15];
    const float* g1   = (const float*)d_in[16];
    const float* be1  = (const float*)d_in[17];
    const float* g2   = (const float*)d_in[18];
    const float* be2  = (const float*)d_in[19];
    float* out = (float*)d_out;

    // Workspace layout. Aliasing (stream-serialized):
    //   tbufB bf16 (11.1MB) aliases srcB (dead after value GEMM)
    //   src2 fp32 (22.3MB)  aliases olg  (dead after meta)
    //   meta (44.6MB)       aliases h    (h written at FFN1, meta consumed)
    char* wsp = (char*)d_ws;
    unsigned short* srcB = (unsigned short*)wsp; wsp += NT256 * 2;
    unsigned short* qB   = (unsigned short*)wsp; wsp += NT256 * 2;
    unsigned short* tbufB = srcB;
    __half*         valB = (__half*)wsp;         wsp += NT256 * 2;
    float*          olg  = (float*)wsp;          wsp += (size_t)NTOK * 384 * 4;
    float*          src2 = olg;
    unsigned short* aoB  = (unsigned short*)wsp; wsp += NT256 * 2;
    unsigned short* xB   = (unsigned short*)wsp; wsp += NT256 * 2;
    unsigned short* h    = (unsigned short*)wsp; wsp += (size_t)NTOK * 1024 * 2;
    uint4*          meta = (uint4*)h;
    unsigned short* WvT  = (unsigned short*)wsp; wsp += 256 * 256 * 2;
    unsigned short* WcatT= (unsigned short*)wsp; wsp += 384 * 256 * 2;
    unsigned short* WoT  = (unsigned short*)wsp; wsp += 256 * 256 * 2;
    unsigned short* W1T  = (unsigned short*)wsp; wsp += 1024 * 256 * 2;
    unsigned short* W2T  = (unsigned short*)wsp; wsp += 256 * 1024 * 2;

    const dim3 blk(256);

    prep_kernel<<<dim3(NT256 / 1024), blk, 0, stream>>>(src, pos, srcB, qB);
    transpose_all_kernel<<<dim3(184), blk, 0, stream>>>(
        Wv, Woff, Wa, Wo, W1, W2, WvT, WcatT, WoT, W1T, W2T);

    // 1. value = src @ Wv + bv  (fp16 out for sampler)
    gemm_mk_kernel<256, 64, 4, false, 2><<<dim3(4 * GYP), blk, 0, stream>>>(
        srcB, WvT, bv, bv, 1 << 30, valB, 256);
    // 2. olg = q @ [Woff|Wa] + [boff|ba]  (fp32, N=384, bias split at 256)
    gemm_mk_kernel<256, 64, 6, false, 0><<<dim3(6 * GYP), blk, 0, stream>>>(
        qB, WcatT, boff, ba, 256, olg, 384);
    // 3. meta: per-point fused softmax/coords -> packed idx+weights
    msda_meta_kernel<<<dim3(NTOK * 128 / 256), blk, 0, stream>>>(olg, meta);
    // 4. sampling gather -> attn_out (bf16), batch-per-XCD-pair swizzle
    msda_sample_kernel<<<dim3(NTOK / 8), blk, 0, stream>>>(valB, meta, aoB);
    // 5. src2 = attn_out @ Wo + bo (fp32, overwrites olg)
    gemm_mk_kernel<256, 64, 4, false, 0><<<dim3(4 * GYP), blk, 0, stream>>>(
        aoB, WoT, bo, bo, 1 << 30, src2, 256);
    // 6. xB = bf16(LN(src + src2))
    ln_kernel<false, false, false, true><<<dim3(NTOK / 4), blk, 0, stream>>>(
        src, src2, g1, be1, nullptr, xB);
    // 7. h = relu(xB @ W1 + b1) (bf16; overwrites meta region — consumed)
    gemm_mk_kernel<256, 64, 16, true, 1><<<dim3(16 * GYP), blk, 0, stream>>>(
        xB, W1T, b1, b1, 1 << 30, h, 1024);
    // 8. t = h @ W2 + b2 (bf16; K=1024, 32-col strips, 65KB LDS -> 2 blk/CU)
    gemm_mk_kernel<1024, 32, 8, false, 1><<<dim3(8 * GYP), blk, 0, stream>>>(
        h, W2T, b2, b2, 1 << 30, tbufB, 256);
    // 9. out = LN(xB + t)
    ln_kernel<true, true, true, false><<<dim3(NTOK / 4), blk, 0, stream>>>(
        xB, tbufB, g2, be2, out, nullptr);
}